// Round 2
// baseline (2770.452 us; speedup 1.0000x reference)
//
#include <hip/hip_runtime.h>
#include <hip/hip_bf16.h>

// Problem constants
#define NB 1024      // batch
#define NT 120       // seq len
#define NE 50        // embed
#define NH 300       // hidden
#define KX 64        // padded x K (50 -> 64): k-chunks 0..1
#define KH 320       // padded h K (300 -> 320): k-chunks 2..11
#define KT 384       // total padded K (12 chunks of 32)
#define HP 320       // padded h-cols per gate in WpT
#define NROWT 16     // row tiles of 64 batch rows
#define NCOLT 19     // col tiles of 16 hidden cols (19*16=304 >= 300)
#define NGEMM 304    // NROWT * NCOLT
#define NPREDB 20    // prediction blocks: 20*256 = 5120 = 1024*5 tasks
#define CSTRIDE 304  // fp32 cell-state row stride
#define XLS_STRIDE 72 // LDS x-tile row stride (64 + 8 pad -> 2-way bank aliasing, free)

typedef __bf16 bf16_t;
typedef __bf16 bf16x8 __attribute__((ext_vector_type(8)));
typedef float f32x4 __attribute__((ext_vector_type(4)));

__device__ __forceinline__ float sigmoidf_(float x) { return 1.0f / (1.0f + expf(-x)); }

// Build WpT[col][k]: col = g*HP + hc (g = gate i/j/f/o, hc = hidden col),
// k in padded space:
//   k 0..49    -> W row k        (x weights)
//   k 50..63   -> 0
//   k 64..363  -> W row k-14     (h weights for h[0..299])
//   k 364..383 -> 0
__global__ void prep_w(const float* __restrict__ W, bf16_t* __restrict__ WpT) {
    int gid = blockIdx.x * 256 + threadIdx.x;
    if (gid >= 4 * HP * KT) return;
    int k = gid % KT;
    int col = gid / KT;
    int g = col / HP, hc = col % HP;
    int kp = -1;
    if (k < 50) kp = k;
    else if (k >= 64 && k < 364) kp = k - 14;
    float v = 0.0f;
    if (kp >= 0 && hc < NH) v = W[(long)kp * 1200 + g * NH + hc];
    WpT[gid] = (bf16_t)v;
}

__global__ void prep_zero(uint4* __restrict__ p, int n) {
    int gid = blockIdx.x * 256 + threadIdx.x;
    if (gid < n) p[gid] = make_uint4(0u, 0u, 0u, 0u);
}

// One LSTM timestep. Blocks 0..303: GEMM+gates for a 64-row x 16-col tile
// (all 4 gates in registers). Blocks 304..323: preds[t-1] = h_{t-1} @ U + b2
// (h_{t-1} is the read buffer of this step -> stable, race-free).
__global__ void __launch_bounds__(256) lstm_step(
    int t,
    const int* __restrict__ ids, const float* __restrict__ emb,
    const float* __restrict__ bl, const bf16_t* __restrict__ WpT,
    const bf16_t* __restrict__ Hr, bf16_t* __restrict__ Hw,
    float* __restrict__ Cst,
    const float* __restrict__ U, const float* __restrict__ b2,
    float* __restrict__ out)
{
    const int blk = blockIdx.x;
    const int tid = threadIdx.x;

    if (blk < NGEMM) {
        __shared__ bf16_t Xls[64 * XLS_STRIDE];
        const int rowTile = blk / NCOLT;
        const int hcTile  = blk % NCOLT;

        // Stage x_t for rows rowTile*64..+63 into LDS (embedding gather + pad).
        {
            int row = tid >> 2;     // 0..63 (local)
            int q   = tid & 3;      // 16-element segment
            int b   = rowTile * 64 + row;
            int id  = ids[b * NT + t];   // input_ids[b][t][0]
            const float* erow = emb + (long)id * NE;
            bf16_t* dst = Xls + row * XLS_STRIDE + q * 16;
#pragma unroll
            for (int j = 0; j < 16; ++j) {
                int e = q * 16 + j;
                float v = (e < NE) ? erow[e] : 0.0f;
                dst[j] = (bf16_t)v;
            }
        }
        __syncthreads();

        const int wave = tid >> 6;
        const int lane = tid & 63;
        const int m    = lane & 15;   // A row-in-16 / B col-in-16 / C-D col
        const int quad = lane >> 4;   // k-slice quarter / C-D row group
        const int rowBase = rowTile * 64 + wave * 16;
        const int myRow = rowBase + m;
        const int hcOut = hcTile * 16 + m;    // up to 303; WpT pads to 320
        const bool colOK = (hcOut < NH);

        float bias0 = 0.f, bias1 = 0.f, bias2 = 0.f, bias3 = 0.f;
        if (colOK) {
            bias0 = bl[hcOut];
            bias1 = bl[NH + hcOut];
            bias2 = bl[2 * NH + hcOut];
            bias3 = bl[3 * NH + hcOut];
        }

        const bf16x8* Wv = (const bf16x8*)WpT;
        int bbase[4];
#pragma unroll
        for (int g = 0; g < 4; ++g)
            bbase[g] = (g * HP + hcOut) * (KT / 8);

        f32x4 acc[4];
#pragma unroll
        for (int g = 0; g < 4; ++g) acc[g] = (f32x4){0.f, 0.f, 0.f, 0.f};

        // x part: k-chunks 0..1 from LDS
        const bf16_t* Xrow = Xls + (wave * 16 + m) * XLS_STRIDE;
#pragma unroll
        for (int kk = 0; kk < 2; ++kk) {
            bf16x8 a = *(const bf16x8*)(Xrow + kk * 32 + quad * 8);
#pragma unroll
            for (int g = 0; g < 4; ++g)
                acc[g] = __builtin_amdgcn_mfma_f32_16x16x32_bf16(
                    a, Wv[bbase[g] + kk * 4 + quad], acc[g], 0, 0, 0);
        }
        // h part: k-chunks 2..11 from global Hr
        const bf16x8* Av_h = (const bf16x8*)(Hr + (long)myRow * KH);
#pragma unroll
        for (int kk = 2; kk < 12; ++kk) {
            bf16x8 a = Av_h[(kk - 2) * 4 + quad];
#pragma unroll
            for (int g = 0; g < 4; ++g)
                acc[g] = __builtin_amdgcn_mfma_f32_16x16x32_bf16(
                    a, Wv[bbase[g] + kk * 4 + quad], acc[g], 0, 0, 0);
        }

        // Gate nonlinearity + state update.
        // C/D layout: col = lane&15 (= m = hcOut col), row = quad*4 + r.
        if (colOK) {
#pragma unroll
            for (int r = 0; r < 4; ++r) {
                int row = rowBase + quad * 4 + r;
                float zi = acc[0][r] + bias0;
                float zj = acc[1][r] + bias1;
                float zf = acc[2][r] + bias2;
                float zo = acc[3][r] + bias3;
                float c  = Cst[(long)row * CSTRIDE + hcOut];
                float cn = c * sigmoidf_(zf + 1.0f) + sigmoidf_(zi) * tanhf(zj);
                Cst[(long)row * CSTRIDE + hcOut] = cn;
                float hn = tanhf(cn) * sigmoidf_(zo);
                Hw[(long)row * KH + hcOut] = (bf16_t)hn;
            }
        }
    } else {
        // preds[t-1] = h_{t-1} @ U + b2  (h_{t-1} == Hr of this step)
        if (t == 0) return;
        int task = (blk - NGEMM) * 256 + tid;   // 0..5119
        int row = task / 5;
        int cls = task - row * 5;
        const bf16_t* hrow = Hr + (long)row * KH;
        float s0 = 0.f, s1 = 0.f, s2 = 0.f, s3 = 0.f;
        for (int k = 0; k < NH; k += 4) {
            s0 += (float)hrow[k]     * U[(k) * 5 + cls];
            s1 += (float)hrow[k + 1] * U[(k + 1) * 5 + cls];
            s2 += (float)hrow[k + 2] * U[(k + 2) * 5 + cls];
            s3 += (float)hrow[k + 3] * U[(k + 3) * 5 + cls];
        }
        out[(long)(t - 1) * (NB * 5) + row * 5 + cls] = s0 + s1 + s2 + s3 + b2[cls];
    }
}

// Final prediction for t = NT-1 (its h buffer is stable after the last step).
__global__ void __launch_bounds__(256) pred_last(
    const bf16_t* __restrict__ H, const float* __restrict__ U,
    const float* __restrict__ b2, float* __restrict__ out)
{
    int task = blockIdx.x * 256 + threadIdx.x;   // 0..5119
    int row = task / 5;
    int cls = task - row * 5;
    const bf16_t* hrow = H + (long)row * KH;
    float s0 = 0.f, s1 = 0.f, s2 = 0.f, s3 = 0.f;
    for (int k = 0; k < NH; k += 4) {
        s0 += (float)hrow[k]     * U[(k) * 5 + cls];
        s1 += (float)hrow[k + 1] * U[(k + 1) * 5 + cls];
        s2 += (float)hrow[k + 2] * U[(k + 2) * 5 + cls];
        s3 += (float)hrow[k + 3] * U[(k + 3) * 5 + cls];
    }
    out[(long)(NT - 1) * (NB * 5) + row * 5 + cls] = s0 + s1 + s2 + s3 + b2[cls];
}

extern "C" void kernel_launch(void* const* d_in, const int* in_sizes, int n_in,
                              void* d_out, int out_size, void* d_ws, size_t ws_size,
                              hipStream_t stream) {
    const int* ids   = (const int*)d_in[0];
    const float* emb = (const float*)d_in[1];
    const float* W   = (const float*)d_in[2];
    const float* bl  = (const float*)d_in[3];
    const float* U   = (const float*)d_in[4];
    const float* b2  = (const float*)d_in[5];
    float* out = (float*)d_out;

    // ws layout (total ~3.4 MB):
    char* ws = (char*)d_ws;
    bf16_t* WpT = (bf16_t*)ws;                         // 4*320*384*2 = 983,040 B
    bf16_t* H0  = (bf16_t*)(ws + 983040);              // 1024*320*2  = 655,360 B
    bf16_t* H1  = (bf16_t*)(ws + 983040 + 655360);     // 655,360 B
    float*  Cst = (float*)(ws + 983040 + 2 * 655360);  // 1024*304*4  = 1,245,184 B

    prep_w<<<(4 * HP * KT + 255) / 256, 256, 0, stream>>>(W, WpT);
    // zero H0, H1, Cst (contiguous): 2*655,360 + 1,245,184 = 2,555,904 B
    int nzero = 2555904 / 16;
    prep_zero<<<(nzero + 255) / 256, 256, 0, stream>>>((uint4*)H0, nzero);

    for (int t = 0; t < NT; ++t) {
        const bf16_t* Hr = (t & 1) ? H1 : H0;
        bf16_t* Hw       = (t & 1) ? H0 : H1;
        lstm_step<<<NGEMM + NPREDB, 256, 0, stream>>>(
            t, ids, emb, bl, WpT, Hr, Hw, Cst, U, b2, out);
    }
    // step t=119 wrote Hw = H0 (119 odd)
    pred_last<<<NPREDB, 256, 0, stream>>>(H0, U, b2, out);
}